// Round 10
// baseline (498.903 us; speedup 1.0000x reference)
//
#include <hip/hip_runtime.h>
#include <hip/hip_cooperative_groups.h>
#include <hip/hip_bf16.h>

namespace cg = cooperative_groups;

#define S 2048
#define D 1024
#define NH 16
#define HD 64
#define NE 65536
#define DH 512
#define SLOTS 128

typedef __attribute__((ext_vector_type(8))) short short8;
typedef __attribute__((ext_vector_type(4))) float f32x4;

#define MFMA16(a, b, c) __builtin_amdgcn_mfma_f32_16x16x32_bf16(a, b, c, 0, 0, 0)

__device__ __forceinline__ unsigned short f2bf(float f) {
    __hip_bfloat16 h = __float2bfloat16(f);
    return *reinterpret_cast<unsigned short*>(&h);
}
__device__ __forceinline__ float bf2f(unsigned short u) {
    unsigned int x = ((unsigned int)u) << 16;
    return *reinterpret_cast<float*>(&x);
}

__device__ __forceinline__ void gload16(const unsigned short* g, unsigned short* l) {
    __builtin_amdgcn_global_load_lds(
        (const __attribute__((address_space(1))) unsigned int*)g,
        (__attribute__((address_space(3))) unsigned int*)l, 16, 0, 0);
}

struct Params {
    const float *x, *nt, *st;
    const float *Wq, *bq, *Wk, *bk, *Wv, *bv, *Wo, *bo;
    const float *Wn1, *bn1, *Wn2, *bn2, *ln_g, *ln_b;
    const int* ei;
    unsigned short *xb, *wb, *qb, *kb, *vb, *pvb;
    float *hidden, *ntwT, *vsumf, *biasAll, *cval, *proj, *attn, *y;
    int *rowcnt, *cpack;
};

__global__ __launch_bounds__(256, 2) void k_mega(Params p) {
    __shared__ __align__(16) unsigned char smem[32768];
    cg::grid_group grid = cg::this_grid();
    const int tid = threadIdx.x;
    const int nb = gridDim.x, bid = blockIdx.x;
    const int w = tid >> 6, lane = tid & 63;
    const int l15 = lane & 15, lhi = lane >> 4;

    // ================= phase A: prep (8192 units) =================
    for (int u = bid; u < 8192; u += nb) {
        int row = u & 1023, z = u >> 10;
        if (z == 5) {
            if (row < 14) {
                int g = row * 256 + tid;
                float v = (g < 1024) ? p.bq[g]
                        : (g < 2048) ? p.bk[g - 1024]
                        : (g < 3072) ? p.bv[g - 2048] : p.bn1[g - 3072];
                p.biasAll[g] = v;
            } else if (row >= 16 && row < 24) {
                p.rowcnt[(row - 16) * 256 + tid] = 0;
            } else if (row >= 24 && row < 28) {
                p.vsumf[(row - 24) * 256 + tid] = 0.f;
            }
            continue;
        }
        if (z >= 6) {
            int s = (z - 6) * 1024 + row;
            const float* r = p.x + (long)s * 1024;
            unsigned short* o = p.xb + (long)s * 1024;
#pragma unroll
            for (int j = 0; j < 4; j++) o[tid * 4 + j] = f2bf(r[tid * 4 + j]);
            continue;
        }
        if (z == 3 && row >= DH) continue;
        const float* src;
        long stride = 1024;
        if (z == 0) src = p.Wq;
        else if (z == 1) src = p.Wk;
        else if (z == 2) src = p.Wv;
        else if (z == 3) { src = p.Wn1; stride = 1026; }
        else src = p.Wo;
        const float* r = src + (long)row * stride;
        unsigned short* o = p.wb + (long)z * 1048576 + (long)row * 1024;
#pragma unroll
        for (int j = 0; j < 4; j++) o[tid * 4 + j] = f2bf(r[tid * 4 + j]);
    }
    grid.sync();

    // ================= phase B: fused GEMM (448 tiles) + edge scatter (16) =================
    {
        unsigned short* Als = (unsigned short*)smem;            // 16 KB
        unsigned short* Bls = (unsigned short*)(smem + 16384);  // 16 KB
        const int wr = w >> 1, wc = w & 1;
        for (int u = bid; u < 464; u += nb) {
            if (u >= 448) {
                int base = (u - 448) * 4096 + tid;
#pragma unroll
                for (int k = 0; k < 16; k++) {
                    int e = base + k * 256;
                    int r = p.ei[e], c = p.ei[NE + e];
                    int i = atomicAdd(&p.rowcnt[r], 1);
                    if (i < SLOTS) {
                        p.cpack[r * SLOTS + i] = ((e + 1) << 11) | c;
                        p.cval[r * SLOTS + i] = p.st[e];
                    }
                }
                continue;
            }
            const int m0 = (u & 15) * 128, n0 = (u >> 4) * 128;
            f32x4 acc[4][4] = {};
            for (int kt = 0; kt < 16; kt++) {
                __syncthreads();
#pragma unroll
                for (int i = 0; i < 4; i++) {
                    int reg = i * 4 + w;
                    int idx = reg * 64 + lane;
                    int row = idx >> 3, c8 = (idx & 7) * 8;
                    gload16(p.xb + (long)(m0 + row) * 1024 + kt * 64 + c8, Als + reg * 512);
                    gload16(p.wb + (long)(n0 + row) * 1024 + kt * 64 + c8, Bls + reg * 512);
                }
                asm volatile("s_waitcnt vmcnt(0)");
                __syncthreads();
#pragma unroll
                for (int kk = 0; kk < 2; kk++) {
                    short8 a[4], b[4];
#pragma unroll
                    for (int mi = 0; mi < 4; mi++)
                        a[mi] = *reinterpret_cast<const short8*>(Als + (wr * 64 + mi * 16 + l15) * 64 + kk * 32 + lhi * 8);
#pragma unroll
                    for (int ni = 0; ni < 4; ni++)
                        b[ni] = *reinterpret_cast<const short8*>(Bls + (wc * 64 + ni * 16 + l15) * 64 + kk * 32 + lhi * 8);
#pragma unroll
                    for (int mi = 0; mi < 4; mi++)
#pragma unroll
                        for (int ni = 0; ni < 4; ni++)
                            acc[mi][ni] = MFMA16(a[mi], b[ni], acc[mi][ni]);
                }
            }
#pragma unroll
            for (int ni = 0; ni < 4; ni++) {
                int n = n0 + wc * 64 + ni * 16 + l15;
                float bb = p.biasAll[n];
                float colsum = 0.f;
#pragma unroll
                for (int mi = 0; mi < 4; mi++) {
#pragma unroll
                    for (int r = 0; r < 4; r++) {
                        int m = m0 + wr * 64 + mi * 16 + lhi * 4 + r;
                        float v = acc[mi][ni][r] + bb;
                        colsum += v;
                        if (n < 3072) {
                            int z = n >> 10, c = n & 1023;
                            int hh = c >> 6, hd = c & 63;
                            unsigned short* dst = (z == 0) ? p.qb : ((z == 1) ? p.kb : p.vb);
                            dst[(long)hh * S * HD + (long)m * HD + hd] = f2bf(v);
                        } else {
                            p.hidden[(long)m * DH + (n - 3072)] = v;
                        }
                    }
                }
                if (n >= 2048 && n < 3072) {
                    colsum += __shfl_xor(colsum, 16);
                    colsum += __shfl_xor(colsum, 32);
                    if (lhi == 0) atomicAdd(&p.vsumf[n - 2048], colsum);
                }
            }
        }
    }
    grid.sync();

    // ================= phase C: node-type MLP tail (2048 rows) =================
    {
        float* rh = (float*)smem;                       // 2048 B
        float (*part)[17] = (float(*)[17])(smem + 2048);  // 1088 B
        for (int s = bid; s < 2048; s += nb) {
            float nt0 = p.nt[s * 2 + 0], nt1 = p.nt[s * 2 + 1];
            for (int j = tid; j < DH; j += 256) {
                float v = p.hidden[(long)s * DH + j] + nt0 * p.Wn1[(long)j * 1026 + 1024]
                        + nt1 * p.Wn1[(long)j * 1026 + 1025];
                rh[j] = fmaxf(v, 0.f);
            }
            __syncthreads();
            {
                int hh = tid & 15, ch = tid >> 4;
                float p2 = 0.f;
#pragma unroll
                for (int j = 0; j < 32; j++) p2 += rh[ch * 32 + j] * p.Wn2[hh * DH + ch * 32 + j];
                part[ch][hh] = p2;
            }
            __syncthreads();
            if (tid < 16) {
                float l = p.bn2[tid];
#pragma unroll
                for (int c = 0; c < 16; c++) l += part[c][tid];
                float mx = l;
#pragma unroll
                for (int m = 1; m < 16; m <<= 1) mx = fmaxf(mx, __shfl_xor(mx, m));
                float e = __expf(l - mx);
                float sum = e;
#pragma unroll
                for (int m = 1; m < 16; m <<= 1) sum += __shfl_xor(sum, m);
                p.ntwT[tid * S + s] = e / sum;
            }
            __syncthreads();
        }
    }
    grid.sync();

    // ================= phase D: sparse attention + row fill (8192 units) =================
    {
        int (*c_lds)[SLOTS] = (int(*)[SLOTS])smem;                          // 2 KB
        float (*pd_lds)[SLOTS] = (float(*)[SLOTS])(smem + 2048);            // 2 KB
        unsigned char (*alive_lds)[SLOTS] = (unsigned char(*)[SLOTS])(smem + 4096);  // 512 B
        const int i_loc = lane & 15, dpart = lane >> 4;
        for (int u = bid; u < 8192; u += nb) {
            int up = (u & 7) * 1024 + (u >> 3);  // XCD swizzle: 2 heads per XCD
            const int r = up * 4 + w;
            const int h = r >> 11, q = r & 2047;
            const int nnz_raw = p.rowcnt[q];
            const int nnz = nnz_raw < SLOTS ? nnz_raw : SLOTS;
            const int chunks = (nnz + 15) >> 4;

            for (int i = lane; i < nnz; i += 64) c_lds[w][i] = p.cpack[q * SLOTS + i];
            asm volatile("" ::: "memory");

            int myCnt = 0;
            for (int i = lane; i < nnz; i += 64) {
                int pk = c_lds[w][i];
                bool alive = true;
                for (int j = 0; j < nnz; j++) {
                    int pj = c_lds[w][j];
                    if ((((pj ^ pk) & 2047) == 0) && pj > pk) alive = false;
                }
                alive_lds[w][i] = alive ? 1 : 0;
                myCnt += alive ? 1 : 0;
            }
#pragma unroll
            for (int off = 1; off < 64; off <<= 1) myCnt += __shfl_xor(myCnt, off);
            const int nnz_alive = myCnt;
            asm volatile("" ::: "memory");

            float qf[16];
            {
                const unsigned short* qp = p.qb + ((long)h * S + q) * HD + dpart * 16;
                short8 q0 = *reinterpret_cast<const short8*>(qp);
                short8 q1 = *reinterpret_cast<const short8*>(qp + 8);
#pragma unroll
                for (int j = 0; j < 8; j++) {
                    qf[j] = bf2f((unsigned short)q0[j]);
                    qf[8 + j] = bf2f((unsigned short)q1[j]);
                }
            }

            float s_reg[8], e_reg[8];
            int c_reg[8];
            int vmask = 0;
#pragma unroll
            for (int c8 = 0; c8 < 8; c8++) {
                s_reg[c8] = -3.0e38f;
                c_reg[c8] = 0;
                if (c8 < chunks) {
                    int i = c8 * 16 + i_loc;
                    bool inr = i < nnz;
                    int ig = inr ? i : 0;
                    bool valid = inr && alive_lds[w][ig];
                    int c = c_lds[w][ig] & 2047;
                    float vv = p.cval[q * SLOTS + ig];
                    const unsigned short* kp = p.kb + ((long)h * S + c) * HD + dpart * 16;
                    short8 k0 = *reinterpret_cast<const short8*>(kp);
                    short8 k1 = *reinterpret_cast<const short8*>(kp + 8);
                    float dot = 0.f;
#pragma unroll
                    for (int j = 0; j < 8; j++) {
                        dot += qf[j] * bf2f((unsigned short)k0[j]);
                        dot += qf[8 + j] * bf2f((unsigned short)k1[j]);
                    }
                    dot += __shfl_xor(dot, 16);
                    dot += __shfl_xor(dot, 32);
                    if (valid) {
                        s_reg[c8] = dot * 0.125f * p.ntwT[(long)h * S + c] * vv;
                        c_reg[c8] = c;
                        vmask |= 1 << c8;
                    }
                }
            }

            float m = s_reg[0];
#pragma unroll
            for (int c8 = 1; c8 < 8; c8++) m = fmaxf(m, s_reg[c8]);
            m = fmaxf(m, __shfl_xor(m, 1));
            m = fmaxf(m, __shfl_xor(m, 2));
            m = fmaxf(m, __shfl_xor(m, 4));
            m = fmaxf(m, __shfl_xor(m, 8));
            const float gm = fmaxf(m, 0.f);

            float zs = 0.f;
#pragma unroll
            for (int c8 = 0; c8 < 8; c8++) {
                e_reg[c8] = __expf(s_reg[c8] - gm);
                zs += e_reg[c8];
            }
            zs += __shfl_xor(zs, 1);
            zs += __shfl_xor(zs, 2);
            zs += __shfl_xor(zs, 4);
            zs += __shfl_xor(zs, 8);
            const float e0 = __expf(-gm);
            const float Z = zs + (float)(S - nnz_alive) * e0;
            const float inv = 1.0f / Z;
            const float p0 = e0 * inv;

            if (dpart == 0) {
#pragma unroll
                for (int c8 = 0; c8 < 8; c8++) {
                    int i = c8 * 16 + i_loc;
                    if (c8 < chunks && i < nnz)
                        pd_lds[w][i] = ((vmask >> c8) & 1) ? e_reg[c8] * inv - p0 : 0.f;
                }
            }
            asm volatile("" ::: "memory");

            float* arow = p.attn + (long)r * S;
            f32x4* a4 = reinterpret_cast<f32x4*>(arow) + lane;
            const f32x4 f4 = {p0, p0, p0, p0};
#pragma unroll
            for (int uu = 0; uu < 8; uu++) __builtin_nontemporal_store(f4, a4 + uu * 64);
            __threadfence_block();
            if (dpart == 0) {
#pragma unroll
                for (int c8 = 0; c8 < 8; c8++)
                    if ((vmask >> c8) & 1) arow[c_reg[c8]] = e_reg[c8] * inv;
            }

            float vacc = 0.f;
            for (int i = 0; i < nnz; i++) {
                int c = c_lds[w][i] & 2047;
                float pd = pd_lds[w][i];
                vacc += pd * bf2f(p.vb[((long)h * S + c) * HD + lane]);
            }
            vacc += p0 * p.vsumf[h * HD + lane];
            p.pvb[(long)q * D + h * HD + lane] = f2bf(vacc);
        }
    }
    grid.sync();

    // ================= phase E: out projection (256 tiles, 128x64) =================
    {
        unsigned short* Als = (unsigned short*)smem;            // 16 KB
        unsigned short* Bls = (unsigned short*)(smem + 16384);  // 8 KB
        const int wr = w >> 1, wc = w & 1;
        for (int u = bid; u < 256; u += nb) {
            const int m0 = (u & 15) * 128, n0 = (u >> 4) * 64;
            f32x4 acc[4][2] = {};
            for (int kt = 0; kt < 16; kt++) {
                __syncthreads();
#pragma unroll
                for (int i = 0; i < 4; i++) {
                    int reg = i * 4 + w;
                    int idx = reg * 64 + lane;
                    int row = idx >> 3, c8 = (idx & 7) * 8;
                    gload16(p.pvb + (long)(m0 + row) * 1024 + kt * 64 + c8, Als + reg * 512);
                }
#pragma unroll
                for (int i = 0; i < 2; i++) {
                    int reg = i * 4 + w;
                    int idx = reg * 64 + lane;
                    int row = idx >> 3, c8 = (idx & 7) * 8;
                    gload16(p.wb + 4l * 1048576 + (long)(n0 + row) * 1024 + kt * 64 + c8, Bls + reg * 512);
                }
                asm volatile("s_waitcnt vmcnt(0)");
                __syncthreads();
#pragma unroll
                for (int kk = 0; kk < 2; kk++) {
                    short8 a[4], b[2];
#pragma unroll
                    for (int mi = 0; mi < 4; mi++)
                        a[mi] = *reinterpret_cast<const short8*>(Als + (wr * 64 + mi * 16 + l15) * 64 + kk * 32 + lhi * 8);
#pragma unroll
                    for (int ni = 0; ni < 2; ni++)
                        b[ni] = *reinterpret_cast<const short8*>(Bls + (wc * 32 + ni * 16 + l15) * 64 + kk * 32 + lhi * 8);
#pragma unroll
                    for (int mi = 0; mi < 4; mi++)
#pragma unroll
                        for (int ni = 0; ni < 2; ni++)
                            acc[mi][ni] = MFMA16(a[mi], b[ni], acc[mi][ni]);
                }
            }
#pragma unroll
            for (int ni = 0; ni < 2; ni++) {
                int n = n0 + wc * 32 + ni * 16 + l15;
                float bb = p.bo[n];
#pragma unroll
                for (int mi = 0; mi < 4; mi++) {
#pragma unroll
                    for (int r = 0; r < 4; r++) {
                        int m = m0 + wr * 64 + mi * 16 + lhi * 4 + r;
                        p.proj[(long)m * 1024 + n] = acc[mi][ni][r] + bb;
                    }
                }
            }
        }
    }
    grid.sync();

    // ================= phase F: residual + LayerNorm (2048 rows) =================
    {
        float* red = (float*)smem;
        for (int s = bid; s < 2048; s += nb) {
            float4 xv = reinterpret_cast<const float4*>(p.x + (long)s * 1024)[tid];
            float4 pv = reinterpret_cast<const float4*>(p.proj + (long)s * 1024)[tid];
            float t0 = xv.x + pv.x, t1 = xv.y + pv.y, t2 = xv.z + pv.z, t3 = xv.w + pv.w;
            float lsum = t0 + t1 + t2 + t3;
#pragma unroll
            for (int m = 32; m >= 1; m >>= 1) lsum += __shfl_xor(lsum, m);
            if (lane == 0) red[w] = lsum;
            __syncthreads();
            float mean = (red[0] + red[1] + red[2] + red[3]) * (1.0f / 1024.f);
            float d0 = t0 - mean, d1 = t1 - mean, d2 = t2 - mean, d3 = t3 - mean;
            float lvar = d0 * d0 + d1 * d1 + d2 * d2 + d3 * d3;
#pragma unroll
            for (int m = 32; m >= 1; m >>= 1) lvar += __shfl_xor(lvar, m);
            if (lane == 0) red[4 + w] = lvar;
            __syncthreads();
            float var = (red[4] + red[5] + red[6] + red[7]) * (1.0f / 1024.f);
            float rstd = rsqrtf(var + 1e-5f);
            float4 gv = reinterpret_cast<const float4*>(p.ln_g)[tid];
            float4 bv = reinterpret_cast<const float4*>(p.ln_b)[tid];
            float4 out;
            out.x = d0 * rstd * gv.x + bv.x;
            out.y = d1 * rstd * gv.y + bv.y;
            out.z = d2 * rstd * gv.z + bv.z;
            out.w = d3 * rstd * gv.w + bv.w;
            reinterpret_cast<float4*>(p.y + (long)s * 1024)[tid] = out;
            __syncthreads();
        }
    }
}

extern "C" void kernel_launch(void* const* d_in, const int* in_sizes, int n_in,
                              void* d_out, int out_size, void* d_ws, size_t ws_size,
                              hipStream_t stream) {
    char* ws = (char*)d_ws;
    Params p;
    p.x = (const float*)d_in[0];
    p.nt = (const float*)d_in[1];
    p.st = (const float*)d_in[2];
    p.Wq = (const float*)d_in[3];
    p.bq = (const float*)d_in[4];
    p.Wk = (const float*)d_in[5];
    p.bk = (const float*)d_in[6];
    p.Wv = (const float*)d_in[7];
    p.bv = (const float*)d_in[8];
    p.Wo = (const float*)d_in[9];
    p.bo = (const float*)d_in[10];
    p.Wn1 = (const float*)d_in[11];
    p.bn1 = (const float*)d_in[12];
    p.Wn2 = (const float*)d_in[13];
    p.bn2 = (const float*)d_in[14];
    p.ln_g = (const float*)d_in[15];
    p.ln_b = (const float*)d_in[16];
    p.ei = (const int*)d_in[17];

    p.xb = (unsigned short*)(ws);                   // 0..4M
    p.qb = (unsigned short*)(ws + (4l << 20));      // 4..8M  [h][s][hd]
    p.kb = (unsigned short*)(ws + (8l << 20));      // 8..12M [h][s][hd]
    p.vb = (unsigned short*)(ws + (12l << 20));     // 12..16M [h][s][hd]
    p.wb = (unsigned short*)(ws + (16l << 20));     // 16..26M 5 slots
    p.hidden = (float*)(ws + (26l << 20));          // 26..30M
    p.ntwT = (float*)(ws + (30l << 20));            // 30M +128KB [h][s]
    p.rowcnt = (int*)(ws + (30l << 20) + (192l << 10));   // 8KB
    p.vsumf = (float*)(ws + (30l << 20) + (384l << 10));  // 4KB
    p.biasAll = (float*)(ws + (30l << 20) + (448l << 10));  // 14KB
    p.cpack = (int*)(ws + (31l << 20));             // 31..32M
    p.cval = (float*)(ws + (32l << 20));            // 32..33M
    p.pvb = (unsigned short*)(ws + (49l << 20));    // 49..53M bf16 [s][1024]
    p.proj = (float*)(ws + (53l << 20));            // 53..61M

    p.y = (float*)d_out;
    p.attn = (float*)d_out + (long)S * D;  // 2097152

    int maxBlocksPerCU = 2;
    (void)hipOccupancyMaxActiveBlocksPerMultiprocessor(&maxBlocksPerCU,
                                                       (const void*)k_mega, 256, 0);
    if (maxBlocksPerCU < 1) maxBlocksPerCU = 1;
    int grid = maxBlocksPerCU * 256;
    if (grid > 512) grid = 512;

    void* args[] = {&p};
    hipLaunchCooperativeKernel((const void*)k_mega, dim3(grid), dim3(256),
                               args, 0, stream);
}

// Round 11
// 156.231 us; speedup vs baseline: 3.1934x; 3.1934x over previous
//
#include <hip/hip_runtime.h>
#include <hip/hip_bf16.h>

#define S 2048
#define D 1024
#define NH 16
#define HD 64
#define NE 65536
#define DH 512
#define SLOTS 128

typedef __attribute__((ext_vector_type(8))) short short8;
typedef __attribute__((ext_vector_type(4))) float f32x4;

#define MFMA16(a, b, c) __builtin_amdgcn_mfma_f32_16x16x32_bf16(a, b, c, 0, 0, 0)

__device__ __forceinline__ unsigned short f2bf(float f) {
    __hip_bfloat16 h = __float2bfloat16(f);
    return *reinterpret_cast<unsigned short*>(&h);
}
__device__ __forceinline__ float bf2f(unsigned short u) {
    unsigned int x = ((unsigned int)u) << 16;
    return *reinterpret_cast<float*>(&x);
}

// async global->LDS, 16B per lane; LDS dest is wave-uniform base + lane*16
__device__ __forceinline__ void gload16(const unsigned short* g, unsigned short* l) {
    __builtin_amdgcn_global_load_lds(
        (const __attribute__((address_space(1))) unsigned int*)g,
        (__attribute__((address_space(3))) unsigned int*)l, 16, 0, 0);
}

// ---------------- prep: weights->bf16, bias pack, x->bf16, zero rowcnt+vsumf ----------------
// grid (1024, 8): z=0..4 weight mats, z=5 bias/rowcnt/vsumf, z=6,7 x rows
__global__ __launch_bounds__(256) void k_prep(const float* __restrict__ x,
                                              const float* __restrict__ Wq,
                                              const float* __restrict__ Wk,
                                              const float* __restrict__ Wv,
                                              const float* __restrict__ Wn1,
                                              const float* __restrict__ Wo,
                                              const float* __restrict__ bq,
                                              const float* __restrict__ bk,
                                              const float* __restrict__ bv,
                                              const float* __restrict__ bn1,
                                              unsigned short* __restrict__ xb,
                                              unsigned short* __restrict__ wb,
                                              float* __restrict__ biasAll,
                                              int* __restrict__ rowcnt,
                                              float* __restrict__ vsumf) {
    int row = blockIdx.x, z = blockIdx.y, t = threadIdx.x;
    if (z == 5) {
        if (row < 14) {
            int g = row * 256 + t;
            float v = (g < 1024) ? bq[g]
                    : (g < 2048) ? bk[g - 1024]
                    : (g < 3072) ? bv[g - 2048] : bn1[g - 3072];
            biasAll[g] = v;
        } else if (row >= 16 && row < 24) {
            rowcnt[(row - 16) * 256 + t] = 0;
        } else if (row >= 24 && row < 28) {
            vsumf[(row - 24) * 256 + t] = 0.f;
        }
        return;
    }
    if (z >= 6) {
        int s = (z - 6) * 1024 + row;
        const float* r = x + (long)s * 1024;
        unsigned short* o = xb + (long)s * 1024;
#pragma unroll
        for (int j = 0; j < 4; j++) o[t * 4 + j] = f2bf(r[t * 4 + j]);
        return;
    }
    if (z == 3 && row >= DH) return;
    const float* src;
    long stride = 1024;
    if (z == 0) src = Wq;
    else if (z == 1) src = Wk;
    else if (z == 2) src = Wv;
    else if (z == 3) { src = Wn1; stride = 1026; }
    else src = Wo;
    const float* r = src + (long)row * stride;
    unsigned short* o = wb + (long)z * 1048576 + (long)row * 1024;
#pragma unroll
    for (int j = 0; j < 4; j++) o[t * 4 + j] = f2bf(r[t * 4 + j]);
}

// ---------------- fused QKV+hidden GEMM (+CSR scatter plane, +Vsum epilogue) ----------------
// grid (16, 29) = 464 units. u<448: GEMM tiles remapped with a bijective XCD
// swizzle (448%8==0) so each XCD owns a contiguous n-band: W-slice ~0.9MB + A
// 4MB resident in its private L2. u>=448: edge scatter (hidden under GEMM).
__global__ __launch_bounds__(256) void k_gemm_fused(const unsigned short* __restrict__ A,
                                                    const unsigned short* __restrict__ Bw,
                                                    const float* __restrict__ biasAll,
                                                    const int* __restrict__ ei,
                                                    const float* __restrict__ st,
                                                    int* __restrict__ rowcnt,
                                                    int* __restrict__ cpack,
                                                    float* __restrict__ cval,
                                                    float* __restrict__ vsumf,
                                                    unsigned short* __restrict__ qout,
                                                    unsigned short* __restrict__ kout,
                                                    unsigned short* __restrict__ vout,
                                                    float* __restrict__ hidden) {
    const int u = blockIdx.y * 16 + blockIdx.x;
    if (u >= 448) {
        int base = (u - 448) * 4096 + threadIdx.x;
#pragma unroll
        for (int k = 0; k < 16; k++) {
            int e = base + k * 256;
            int r = ei[e], c = ei[NE + e];
            int i = atomicAdd(&rowcnt[r], 1);
            if (i < SLOTS) {
                cpack[r * SLOTS + i] = ((e + 1) << 11) | c;
                cval[r * SLOTS + i] = st[e];
            }
        }
        return;
    }
    __shared__ unsigned short Als[128 * 64];
    __shared__ unsigned short Bls[128 * 64];
    const int tid = threadIdx.x, w = tid >> 6, lane = tid & 63;
    const int l15 = lane & 15, lhi = lane >> 4;
    const int wr = w >> 1, wc = w & 1;
    const int t = (u & 7) * 56 + (u >> 3);  // XCD swizzle: XCD i owns tiles [i*56, i*56+56)
    const int m0 = (t & 15) * 128, n0 = (t >> 4) * 128;
    f32x4 acc[4][4] = {};
    for (int kt = 0; kt < 16; kt++) {
        __syncthreads();
#pragma unroll
        for (int i = 0; i < 4; i++) {
            int reg = i * 4 + w;
            int idx = reg * 64 + lane;
            int row = idx >> 3, c8 = (idx & 7) * 8;
            gload16(A + (long)(m0 + row) * 1024 + kt * 64 + c8, Als + reg * 512);
            gload16(Bw + (long)(n0 + row) * 1024 + kt * 64 + c8, Bls + reg * 512);
        }
        asm volatile("s_waitcnt vmcnt(0)");
        __syncthreads();
#pragma unroll
        for (int kk = 0; kk < 2; kk++) {
            short8 a[4], b[4];
#pragma unroll
            for (int mi = 0; mi < 4; mi++)
                a[mi] = *reinterpret_cast<const short8*>(Als + (wr * 64 + mi * 16 + l15) * 64 + kk * 32 + lhi * 8);
#pragma unroll
            for (int ni = 0; ni < 4; ni++)
                b[ni] = *reinterpret_cast<const short8*>(Bls + (wc * 64 + ni * 16 + l15) * 64 + kk * 32 + lhi * 8);
#pragma unroll
            for (int mi = 0; mi < 4; mi++)
#pragma unroll
                for (int ni = 0; ni < 4; ni++)
                    acc[mi][ni] = MFMA16(a[mi], b[ni], acc[mi][ni]);
        }
    }
#pragma unroll
    for (int ni = 0; ni < 4; ni++) {
        int n = n0 + wc * 64 + ni * 16 + l15;
        float bb = biasAll[n];
        float colsum = 0.f;
#pragma unroll
        for (int mi = 0; mi < 4; mi++) {
#pragma unroll
            for (int r = 0; r < 4; r++) {
                int m = m0 + wr * 64 + mi * 16 + lhi * 4 + r;
                float v = acc[mi][ni][r] + bb;
                colsum += v;
                if (n < 3072) {
                    int z = n >> 10, c = n & 1023;
                    int hh = c >> 6, hd = c & 63;
                    unsigned short* dst = (z == 0) ? qout : ((z == 1) ? kout : vout);
                    dst[(long)hh * S * HD + (long)m * HD + hd] = f2bf(v);
                } else {
                    hidden[(long)m * DH + (n - 3072)] = v;
                }
            }
        }
        if (n >= 2048 && n < 3072) {  // V region: column sums for p0*Vsum
            colsum += __shfl_xor(colsum, 16);
            colsum += __shfl_xor(colsum, 32);
            if (lhi == 0) atomicAdd(&vsumf[n - 2048], colsum);
        }
    }
}

// ---------------- out projection GEMM: 128x64 tile (256 blocks, XCD-swizzled) ----------------
__global__ __launch_bounds__(256) void k_gemm_out(const unsigned short* __restrict__ A,
                                                  const unsigned short* __restrict__ Bw,
                                                  const float* __restrict__ bo,
                                                  float* __restrict__ proj) {
    __shared__ unsigned short Als[128 * 64];
    __shared__ unsigned short Bls[64 * 64];
    const int tid = threadIdx.x, w = tid >> 6, lane = tid & 63;
    const int l15 = lane & 15, lhi = lane >> 4;
    const int wr = w >> 1, wc = w & 1;
    const int u = blockIdx.y * 16 + blockIdx.x;
    const int t = (u & 7) * 32 + (u >> 3);  // XCD swizzle over 256 tiles
    const int m0 = (t & 15) * 128, n0 = (t >> 4) * 64;
    f32x4 acc[4][2] = {};
    for (int kt = 0; kt < 16; kt++) {
        __syncthreads();
#pragma unroll
        for (int i = 0; i < 4; i++) {
            int reg = i * 4 + w;
            int idx = reg * 64 + lane;
            int row = idx >> 3, c8 = (idx & 7) * 8;
            gload16(A + (long)(m0 + row) * 1024 + kt * 64 + c8, Als + reg * 512);
        }
#pragma unroll
        for (int i = 0; i < 2; i++) {
            int reg = i * 4 + w;
            int idx = reg * 64 + lane;
            int row = idx >> 3, c8 = (idx & 7) * 8;
            gload16(Bw + (long)(n0 + row) * 1024 + kt * 64 + c8, Bls + reg * 512);
        }
        asm volatile("s_waitcnt vmcnt(0)");
        __syncthreads();
#pragma unroll
        for (int kk = 0; kk < 2; kk++) {
            short8 a[4], b[2];
#pragma unroll
            for (int mi = 0; mi < 4; mi++)
                a[mi] = *reinterpret_cast<const short8*>(Als + (wr * 64 + mi * 16 + l15) * 64 + kk * 32 + lhi * 8);
#pragma unroll
            for (int ni = 0; ni < 2; ni++)
                b[ni] = *reinterpret_cast<const short8*>(Bls + (wc * 32 + ni * 16 + l15) * 64 + kk * 32 + lhi * 8);
#pragma unroll
            for (int mi = 0; mi < 4; mi++)
#pragma unroll
                for (int ni = 0; ni < 2; ni++)
                    acc[mi][ni] = MFMA16(a[mi], b[ni], acc[mi][ni]);
        }
    }
#pragma unroll
    for (int ni = 0; ni < 2; ni++) {
        int n = n0 + wc * 32 + ni * 16 + l15;
        float bb = bo[n];
#pragma unroll
        for (int mi = 0; mi < 4; mi++) {
#pragma unroll
            for (int r = 0; r < 4; r++) {
                int m = m0 + wr * 64 + mi * 16 + lhi * 4 + r;
                proj[(long)m * 1024 + n] = acc[mi][ni][r] + bb;
            }
        }
    }
}

// ---------------- node-type MLP tail -> ntwT [h][s] ----------------
__global__ __launch_bounds__(256) void k_ntw(const float* __restrict__ hidden,
                                             const float* __restrict__ Wn1,
                                             const float* __restrict__ nt,
                                             const float* __restrict__ Wn2,
                                             const float* __restrict__ bn2,
                                             float* __restrict__ ntwT) {
    int tid = threadIdx.x;
    int s = blockIdx.x;
    __shared__ float rh[DH];
    __shared__ float part[16][17];
    float nt0 = nt[s * 2 + 0], nt1 = nt[s * 2 + 1];
    for (int j = tid; j < DH; j += 256) {
        float v = hidden[(long)s * DH + j] + nt0 * Wn1[(long)j * 1026 + 1024]
                + nt1 * Wn1[(long)j * 1026 + 1025];
        rh[j] = fmaxf(v, 0.f);
    }
    __syncthreads();
    {
        int hh = tid & 15, ch = tid >> 4;
        float p2 = 0.f;
#pragma unroll
        for (int j = 0; j < 32; j++) p2 += rh[ch * 32 + j] * Wn2[hh * DH + ch * 32 + j];
        part[ch][hh] = p2;
    }
    __syncthreads();
    if (tid < 16) {
        float l = bn2[tid];
#pragma unroll
        for (int c = 0; c < 16; c++) l += part[c][tid];
        float mx = l;
#pragma unroll
        for (int m = 1; m < 16; m <<= 1) mx = fmaxf(mx, __shfl_xor(mx, m));
        float e = __expf(l - mx);
        float sum = e;
#pragma unroll
        for (int m = 1; m < 16; m <<= 1) sum += __shfl_xor(sum, m);
        ntwT[tid * S + s] = e / sum;
    }
}

// ---------------- sparse attention + row fill, one WAVE per (h,q) row ----------------
// CSR contains ALL edges (with dups); dedup in-wave by max packed (eid<<11|c).
__global__ __launch_bounds__(256, 4) void k_sparsefill(const unsigned short* __restrict__ qb,
                                                       const unsigned short* __restrict__ kb,
                                                       const unsigned short* __restrict__ vb,
                                                       const float* __restrict__ ntwT,
                                                       const int* __restrict__ rowcnt,
                                                       const int* __restrict__ cpack,
                                                       const float* __restrict__ cval,
                                                       const float* __restrict__ vsumf,
                                                       float* __restrict__ attn_out,
                                                       unsigned short* __restrict__ pv_out) {
    __shared__ int c_lds[4][SLOTS];
    __shared__ float pd_lds[4][SLOTS];
    __shared__ unsigned char alive_lds[4][SLOTS];
    const int tid = threadIdx.x, w = tid >> 6, lane = tid & 63;
    int b = (int)blockIdx.x;
    b = (b & 7) * 1024 + (b >> 3);  // XCD swizzle: 2 heads per XCD (K/V L2-resident)
    const int r = b * 4 + w;
    const int h = r >> 11, q = r & 2047;
    const int i_loc = lane & 15, dpart = lane >> 4;
    const int nnz_raw = rowcnt[q];
    const int nnz = nnz_raw < SLOTS ? nnz_raw : SLOTS;
    const int chunks = (nnz + 15) >> 4;

    // stage packed entries to LDS
    for (int i = lane; i < nnz; i += 64) c_lds[w][i] = cpack[q * SLOTS + i];
    asm volatile("" ::: "memory");

    // dedup: alive iff no entry with same col and larger eid (numpy last-wins)
    int myCnt = 0;
    for (int i = lane; i < nnz; i += 64) {
        int pk = c_lds[w][i];
        bool alive = true;
        for (int j = 0; j < nnz; j++) {
            int pj = c_lds[w][j];
            if ((((pj ^ pk) & 2047) == 0) && pj > pk) alive = false;
        }
        alive_lds[w][i] = alive ? 1 : 0;
        myCnt += alive ? 1 : 0;
    }
#pragma unroll
    for (int off = 1; off < 64; off <<= 1) myCnt += __shfl_xor(myCnt, off);
    const int nnz_alive = myCnt;
    asm volatile("" ::: "memory");

    // q fragment: 16 dims of this dpart's quarter
    float qf[16];
    {
        const unsigned short* qp = qb + ((long)h * S + q) * HD + dpart * 16;
        short8 q0 = *reinterpret_cast<const short8*>(qp);
        short8 q1 = *reinterpret_cast<const short8*>(qp + 8);
#pragma unroll
        for (int j = 0; j < 8; j++) {
            qf[j] = bf2f((unsigned short)q0[j]);
            qf[8 + j] = bf2f((unsigned short)q1[j]);
        }
    }

    float s_reg[8], e_reg[8];
    int c_reg[8];
    int vmask = 0;
#pragma unroll
    for (int c8 = 0; c8 < 8; c8++) {
        s_reg[c8] = -3.0e38f;
        c_reg[c8] = 0;
        if (c8 < chunks) {
            int i = c8 * 16 + i_loc;
            bool inr = i < nnz;
            int ig = inr ? i : 0;
            bool valid = inr && alive_lds[w][ig];
            int c = c_lds[w][ig] & 2047;
            float vv = cval[q * SLOTS + ig];
            const unsigned short* kp = kb + ((long)h * S + c) * HD + dpart * 16;
            short8 k0 = *reinterpret_cast<const short8*>(kp);
            short8 k1 = *reinterpret_cast<const short8*>(kp + 8);
            float dot = 0.f;
#pragma unroll
            for (int j = 0; j < 8; j++) {
                dot += qf[j] * bf2f((unsigned short)k0[j]);
                dot += qf[8 + j] * bf2f((unsigned short)k1[j]);
            }
            dot += __shfl_xor(dot, 16);
            dot += __shfl_xor(dot, 32);
            if (valid) {
                s_reg[c8] = dot * 0.125f * ntwT[(long)h * S + c] * vv;
                c_reg[c8] = c;
                vmask |= 1 << c8;
            }
        }
    }

    float m = s_reg[0];
#pragma unroll
    for (int c8 = 1; c8 < 8; c8++) m = fmaxf(m, s_reg[c8]);
    m = fmaxf(m, __shfl_xor(m, 1));
    m = fmaxf(m, __shfl_xor(m, 2));
    m = fmaxf(m, __shfl_xor(m, 4));
    m = fmaxf(m, __shfl_xor(m, 8));
    const float gm = fmaxf(m, 0.f);

    float zs = 0.f;
#pragma unroll
    for (int c8 = 0; c8 < 8; c8++) {
        e_reg[c8] = __expf(s_reg[c8] - gm);  // dead/-inf -> 0
        zs += e_reg[c8];
    }
    zs += __shfl_xor(zs, 1);
    zs += __shfl_xor(zs, 2);
    zs += __shfl_xor(zs, 4);
    zs += __shfl_xor(zs, 8);
    const float e0 = __expf(-gm);
    const float Z = zs + (float)(S - nnz_alive) * e0;
    const float inv = 1.0f / Z;
    const float p0 = e0 * inv;

    // pd for PV (dead entries -> 0)
    if (dpart == 0) {
#pragma unroll
        for (int c8 = 0; c8 < 8; c8++) {
            int i = c8 * 16 + i_loc;
            if (c8 < chunks && i < nnz)
                pd_lds[w][i] = ((vmask >> c8) & 1) ? e_reg[c8] * inv - p0 : 0.f;
        }
    }
    asm volatile("" ::: "memory");

    // fill attn row with p0 (non-temporal streaming), then scatter alive values
    float* arow = attn_out + (long)r * S;
    f32x4* a4 = reinterpret_cast<f32x4*>(arow) + lane;
    const f32x4 f4 = {p0, p0, p0, p0};
#pragma unroll
    for (int u = 0; u < 8; u++) __builtin_nontemporal_store(f4, a4 + u * 64);
    __threadfence_block();
    if (dpart == 0) {
#pragma unroll
        for (int c8 = 0; c8 < 8; c8++)
            if ((vmask >> c8) & 1) arow[c_reg[c8]] = e_reg[c8] * inv;
    }

    // PV: lanes = output dim
    float vacc = 0.f;
    for (int i = 0; i < nnz; i++) {
        int c = c_lds[w][i] & 2047;
        float pd = pd_lds[w][i];
        vacc += pd * bf2f(vb[((long)h * S + c) * HD + lane]);
    }
    vacc += p0 * vsumf[h * HD + lane];
    pv_out[(long)q * D + h * HD + lane] = f2bf(vacc);
}

// ---------------- residual + LayerNorm ----------------
__global__ __launch_bounds__(256) void k_ln(const float* __restrict__ x,
                                            const float* __restrict__ proj,
                                            const float* __restrict__ g,
                                            const float* __restrict__ bta,
                                            float* __restrict__ y) {
    int s = blockIdx.x, tid = threadIdx.x;
    int w = tid >> 6, lane = tid & 63;
    __shared__ float red[8];
    float4 xv = reinterpret_cast<const float4*>(x + (long)s * 1024)[tid];
    float4 pv = reinterpret_cast<const float4*>(proj + (long)s * 1024)[tid];
    float t0 = xv.x + pv.x, t1 = xv.y + pv.y, t2 = xv.z + pv.z, t3 = xv.w + pv.w;
    float lsum = t0 + t1 + t2 + t3;
#pragma unroll
    for (int m = 32; m >= 1; m >>= 1) lsum += __shfl_xor(lsum, m);
    if (lane == 0) red[w] = lsum;
    __syncthreads();
    float mean = (red[0] + red[1] + red[2] + red[3]) * (1.0f / 1024.f);
    float d0 = t0 - mean, d1 = t1 - mean, d2 = t2 - mean, d3 = t3 - mean;
    float lvar = d0 * d0 + d1 * d1 + d2 * d2 + d3 * d3;
#pragma unroll
    for (int m = 32; m >= 1; m >>= 1) lvar += __shfl_xor(lvar, m);
    if (lane == 0) red[4 + w] = lvar;
    __syncthreads();
    float var = (red[4] + red[5] + red[6] + red[7]) * (1.0f / 1024.f);
    float rstd = rsqrtf(var + 1e-5f);
    float4 gv = reinterpret_cast<const float4*>(g)[tid];
    float4 bv = reinterpret_cast<const float4*>(bta)[tid];
    float4 out;
    out.x = d0 * rstd * gv.x + bv.x;
    out.y = d1 * rstd * gv.y + bv.y;
    out.z = d2 * rstd * gv.z + bv.z;
    out.w = d3 * rstd * gv.w + bv.w;
    reinterpret_cast<float4*>(y + (long)s * 1024)[tid] = out;
}

extern "C" void kernel_launch(void* const* d_in, const int* in_sizes, int n_in,
                              void* d_out, int out_size, void* d_ws, size_t ws_size,
                              hipStream_t stream) {
    const float* x = (const float*)d_in[0];
    const float* node_types = (const float*)d_in[1];
    const float* stoich = (const float*)d_in[2];
    const float* Wq = (const float*)d_in[3];
    const float* bq = (const float*)d_in[4];
    const float* Wk = (const float*)d_in[5];
    const float* bk = (const float*)d_in[6];
    const float* Wv = (const float*)d_in[7];
    const float* bv = (const float*)d_in[8];
    const float* Wo = (const float*)d_in[9];
    const float* bo = (const float*)d_in[10];
    const float* Wn1 = (const float*)d_in[11];
    const float* bn1 = (const float*)d_in[12];
    const float* Wn2 = (const float*)d_in[13];
    const float* bn2 = (const float*)d_in[14];
    const float* ln_g = (const float*)d_in[15];
    const float* ln_b = (const float*)d_in[16];
    const int* ei = (const int*)d_in[17];

    char* ws = (char*)d_ws;
    unsigned short* x_bf = (unsigned short*)(ws);                 // 0..4M
    unsigned short* q_bf = (unsigned short*)(ws + (4l << 20));    // 4..8M  [h][s][hd]
    unsigned short* k_bf = (unsigned short*)(ws + (8l << 20));    // 8..12M [h][s][hd]
    unsigned short* v_bf = (unsigned short*)(ws + (12l << 20));   // 12..16M [h][s][hd]
    unsigned short* w_bf = (unsigned short*)(ws + (16l << 20));   // 16..26M 5 slots
    float* hidden = (float*)(ws + (26l << 20));                   // 26..30M
    float* ntwT = (float*)(ws + (30l << 20));                     // 30M +128KB [h][s]
    int* rowcnt = (int*)(ws + (30l << 20) + (192l << 10));        // 8KB
    float* vsumf = (float*)(ws + (30l << 20) + (384l << 10));     // 4KB
    float* biasAll = (float*)(ws + (30l << 20) + (448l << 10));   // 14KB
    int* cpack = (int*)(ws + (31l << 20));                        // 31..32M
    float* cval = (float*)(ws + (32l << 20));                     // 32..33M
    unsigned short* pvb = (unsigned short*)(ws + (49l << 20));    // 49..53M bf16 [s][1024]
    float* proj = (float*)(ws + (53l << 20));                     // 53..61M

    float* y_out = (float*)d_out;
    float* attn_out = (float*)d_out + (long)S * D;  // 2097152

    k_prep<<<dim3(1024, 8), 256, 0, stream>>>(x, Wq, Wk, Wv, Wn1, Wo,
                                              bq, bk, bv, bn1, x_bf, w_bf,
                                              biasAll, rowcnt, vsumf);
    k_gemm_fused<<<dim3(16, 29), 256, 0, stream>>>(x_bf, w_bf, biasAll,
                                                   ei, stoich, rowcnt, cpack, cval,
                                                   vsumf, q_bf, k_bf, v_bf, hidden);
    k_ntw<<<2048, 256, 0, stream>>>(hidden, Wn1, node_types, Wn2, bn2, ntwT);
    k_sparsefill<<<8192, 256, 0, stream>>>(q_bf, k_bf, v_bf, ntwT, rowcnt,
                                           cpack, cval, vsumf, attn_out, pvb);
    k_gemm_out<<<dim3(16, 16), 256, 0, stream>>>(pvb, w_bf + 4l * 1048576, bo, proj);
    k_ln<<<2048, 256, 0, stream>>>(x, proj, ln_g, ln_b, y_out);
}